// Round 14
// baseline (172.193 us; speedup 1.0000x reference)
//
#include <hip/hip_runtime.h>
#include <stdint.h>

// Problem constants (from reference): D1=3, S=384, B=32, N=65536
#define NPTS 65536
#define NB   32
#define SS   384

// RN(1/3) in f32 = 0x3EAAAAAB
#define C3INV 0.333333343267440796f

// ---- Forced HW fp atomics (R14) ----
// atomicAdd(float) AND unsafeAtomicAdd both compile to a CAS retry loop on
// this gfx950 toolchain (R13: identical 84us AND bit-identical absmax vs
// atomicAdd => codegen unchanged). 6.29M lane-adds x ~8cyc CAS chain
// /256CU/2.4GHz = 82us = the observed R10-R13 floor, invariant to TLP,
// traffic, iteration count. Emit the native instructions via inline asm.
// LDS: flat->group addrspacecast is a low-32-bit truncate on AMDGCN, so
// the low 32 bits of a generic pointer into __shared__ ARE the ds offset.
__device__ __forceinline__ void lds_fadd(float* p, float v) {
    uint32_t off = (uint32_t)(uintptr_t)p;
    asm volatile("ds_add_f32 %0, %1" :: "v"(off), "v"(v) : "memory");
}
// Global: fire-and-forget HW fp add (no return value needed).
__device__ __forceinline__ void global_fadd(float* p, float v) {
    asm volatile("global_atomic_add_f32 %0, %1, off" :: "v"(p), "v"(v) : "memory");
}

// ---- LOCKED NUMERICS (R7, passed absmax<=0.0156) ----
__device__ __forceinline__ float fmul_strict(float a, float b) {
    float r;
    asm volatile("v_mul_f32 %0, %1, %2" : "=v"(r) : "v"(a), "v"(b));
    return r;
}
__device__ __forceinline__ float fadd_strict(float a, float b) {
    float r;
    asm volatile("v_add_f32 %0, %1, %2" : "=v"(r) : "v"(a), "v"(b));
    return r;
}

__device__ __forceinline__ void lattice_point(
    const float* __restrict__ t,
    float p0, float p1, float p2,
    int& gi0, int& gi1, int& rc0, int& rc1)
{
    float e0 = fadd_strict(fadd_strict(fmul_strict(t[0], p0), fmul_strict(t[1], p1)), fmul_strict(t[2], p2));
    float e1 = fadd_strict(fadd_strict(fmul_strict(t[3], p0), fmul_strict(t[4], p1)), fmul_strict(t[5], p2));
    float e2 = fadd_strict(fadd_strict(fmul_strict(t[6], p0), fmul_strict(t[7], p1)), fmul_strict(t[8], p2));

    float g0 = __fmul_rn(rintf(__fmul_rn(e0, C3INV)), 3.0f);
    float g1 = __fmul_rn(rintf(__fmul_rn(e1, C3INV)), 3.0f);
    float g2 = __fmul_rn(rintf(__fmul_rn(e2, C3INV)), 3.0f);

    float m0 = e0 - g0, m1 = e1 - g1, m2 = e2 - g2;
    int r0 = (int)(m1 > m0) + (int)(m2 > m0);
    int r1 = (int)(m0 >= m1) + (int)(m2 > m1);

    gi0 = (int)g0;
    gi1 = (int)g1;

    const int irs = (gi0 + gi1 + (int)g2) / 3;

    if (irs > 0) {
        if (r0 >= 3 - irs) { gi0 -= 3; r0 -= 3; }
        if (r1 >= 3 - irs) { gi1 -= 3; r1 -= 3; }
    } else if (irs < 0) {
        if (r0 < -irs) { gi0 += 3; r0 += 3; }
        if (r1 < -irs) { gi1 += 3; r1 += 3; }
    }
    r0 += irs;
    r1 += irs;

    if (r0 < 0) r0 += 3;
    if (r1 < 0) r1 += 3;
    rc0 = min(2, max(0, r0));
    rc1 = min(2, max(0, r1));
}

// ceil(a/3) for any sign (exact)
__device__ __forceinline__ int icl3(int a) {
    return (a >= 0) ? (a + 2) / 3 : -((-a) / 3);
}

// ============================ FAST PATH ============================
// Kernel A: float4 pc loads (4 points/lane), uint4 bins store.
__global__ __launch_bounds__(1024) void bin_kernel(
    const float* __restrict__ pc, const float* __restrict__ tmg,
    uint32_t* __restrict__ bins, int* __restrict__ partial)
{
    const int bx  = blockIdx.x;   // 0..15
    const int b   = blockIdx.y;
    const int tid = threadIdx.x;

    __shared__ float t[9];
    if (tid < 9) t[tid] = tmg[b * 9 + tid];
    __syncthreads();

    const float* pcb = pc + (size_t)b * 3 * NPTS;
    const int v = bx * 1024 + tid;           // float4 group index

    const float4 P0 = ((const float4*)(pcb + 0 * NPTS))[v];
    const float4 P1 = ((const float4*)(pcb + 1 * NPTS))[v];
    const float4 P2 = ((const float4*)(pcb + 2 * NPTS))[v];

    int km0 = 0x7FFFFFFF, km1 = 0x7FFFFFFF;
    uint32_t pk[4];
    const float p0a[4] = {P0.x, P0.y, P0.z, P0.w};
    const float p1a[4] = {P1.x, P1.y, P1.z, P1.w};
    const float p2a[4] = {P2.x, P2.y, P2.z, P2.w};
#pragma unroll
    for (int i = 0; i < 4; ++i) {
        int gi0, gi1, rc0, rc1;
        lattice_point(t, p0a[i], p1a[i], p2a[i], gi0, gi1, rc0, rc1);
        pk[i] = (uint32_t)(((gi0 / 3 + 512) << 16) | (gi1 / 3 + 512));
        km0 = min(km0, gi0 - rc0);
        km1 = min(km1, gi1 - rc1);
    }
    ((uint4*)(bins + (size_t)b * NPTS))[v] = make_uint4(pk[0], pk[1], pk[2], pk[3]);

#pragma unroll
    for (int off = 32; off > 0; off >>= 1) {
        km0 = min(km0, __shfl_down(km0, off));
        km1 = min(km1, __shfl_down(km1, off));
    }
    __shared__ int s0[16], s1[16];
    if ((tid & 63) == 0) { s0[tid >> 6] = km0; s1[tid >> 6] = km1; }
    __syncthreads();
    if (tid == 0) {
        int m0 = s0[0], m1 = s1[0];
#pragma unroll
        for (int j = 1; j < 16; ++j) { m0 = min(m0, s0[j]); m1 = min(m1, s1[j]); }
        partial[(b * 16 + bx) * 2 + 0] = m0;
        partial[(b * 16 + bx) * 2 + 1] = m1;
    }
}

// Kernel B: LDS-privatized histogram, TILE_X=32, 16B/lane vector streams,
// HW ds_add_f32 inner adds, HW global_atomic_add_f32 flush.
#define TILE_X 32
#define HIST_F (128 * TILE_X * 3)   // 12288 floats = 49.2 KB

__global__ __launch_bounds__(1024) void splat_bins_kernel(
    const uint32_t* __restrict__ bins, const float* __restrict__ feat,
    const int* __restrict__ partial, float* __restrict__ out)
{
    const int b     = blockIdx.x;     // 0..31 (fastest -> XCD co-location)
    const int tile  = blockIdx.y;     // 0..3
    const int chunk = blockIdx.z;     // 0..1
    const int tid   = threadIdx.x;    // 0..1023

    __shared__ float hist[HIST_F];
#pragma unroll
    for (int i = tid; i < HIST_F; i += 1024) hist[i] = 0.0f;

    int off0 = 0x7FFFFFFF, off1 = 0x7FFFFFFF;
#pragma unroll
    for (int j = 0; j < 16; ++j) {
        off0 = min(off0, partial[(b * 16 + j) * 2 + 0]);
        off1 = min(off1, partial[(b * 16 + j) * 2 + 1]);
    }
    __syncthreads();

    // y = s0 - ceil(off0/3), x = s1 - ceil(off1/3)  (exact; >= 0)
    const int K0 = 512 + icl3(off0);
    const int K1 = 512 + icl3(off1);

    const uint32_t* bb = bins + (size_t)b * NPTS + (size_t)chunk * (NPTS / 2);
    const float* ftb = feat + (size_t)b * 3 * NPTS + (size_t)chunk * (NPTS / 2);

    // 32768 points per block / 1024 lanes / 4 per vector = 8 iterations
#pragma unroll
    for (int i = 0; i < (NPTS / 2) / 4096; ++i) {
        const int v = i * 1024 + tid;
        const uint4  U  = ((const uint4 *)bb)[v];
        const float4 F0 = ((const float4*)(ftb + 0 * NPTS))[v];
        const float4 F1 = ((const float4*)(ftb + 1 * NPTS))[v];
        const float4 F2 = ((const float4*)(ftb + 2 * NPTS))[v];

        const uint32_t ua[4] = {U.x, U.y, U.z, U.w};
        const float f0a[4] = {F0.x, F0.y, F0.z, F0.w};
        const float f1a[4] = {F1.x, F1.y, F1.z, F1.w};
        const float f2a[4] = {F2.x, F2.y, F2.z, F2.w};

#pragma unroll
        for (int k = 0; k < 4; ++k) {
            const int y = (int)(ua[k] >> 16) - K0;
            const int x = (int)(ua[k] & 0xFFFFu) - K1;
            // y<128 == (c0<384); (x>>5)==tile subsumes 0<=x<128
            if (y < 128 && (x >> 5) == tile) {
                const int base = (y * TILE_X + (x & 31)) * 3;
                lds_fadd(&hist[base + 0], f0a[k]);
                lds_fadd(&hist[base + 1], f1a[k]);
                lds_fadd(&hist[base + 2], f2a[k]);
            }
        }
    }
    __syncthreads();

    // Flush: dense coalesced HW global fp atomics into pre-zeroed out.
    const int x0 = tile * TILE_X;
#pragma unroll
    for (int idx = tid; idx < HIST_F; idx += 1024) {
        const int y   = idx / (TILE_X * 3);
        const int rem = idx - y * (TILE_X * 3);
        global_fadd(&out[(size_t)(b * 128 + y) * 384 + x0 * 3 + rem], hist[idx]);
    }
}

// ========================= FALLBACK PATH ==========================
// Only if ws_size < bins+partial (never observed). 64 ints of ws.
#define FTILE_X 16
#define FHIST_F (128 * FTILE_X * 3)

__global__ __launch_bounds__(1024) void kmin2_kernel(
    const float* __restrict__ pc, const float* __restrict__ tmg,
    int* __restrict__ mins)
{
    const int b = blockIdx.y, bx = blockIdx.x, tid = threadIdx.x;
    __shared__ float t[9];
    if (tid < 9) t[tid] = tmg[b * 9 + tid];
    __syncthreads();

    const float* pcb = pc + (size_t)b * 3 * NPTS;
    int km0 = 0x7FFFFFFF, km1 = 0x7FFFFFFF;
    const int n0 = bx * 8192;
#pragma unroll
    for (int i = 0; i < 8; ++i) {
        const int n = n0 + i * 1024 + tid;
        int gi0, gi1, rc0, rc1;
        lattice_point(t, pcb[n], pcb[NPTS + n], pcb[2 * NPTS + n], gi0, gi1, rc0, rc1);
        km0 = min(km0, gi0 - rc0);
        km1 = min(km1, gi1 - rc1);
    }
#pragma unroll
    for (int off = 32; off > 0; off >>= 1) {
        km0 = min(km0, __shfl_down(km0, off));
        km1 = min(km1, __shfl_down(km1, off));
    }
    __shared__ int s0[16], s1[16];
    if ((tid & 63) == 0) { s0[tid >> 6] = km0; s1[tid >> 6] = km1; }
    __syncthreads();
    if (tid == 0) {
        int m0 = s0[0], m1 = s1[0];
#pragma unroll
        for (int j = 1; j < 16; ++j) { m0 = min(m0, s0[j]); m1 = min(m1, s1[j]); }
        atomicMin(&mins[b * 2 + 0], m0);
        atomicMin(&mins[b * 2 + 1], m1);
    }
}

__global__ __launch_bounds__(1024) void splat_recompute_kernel(
    const float* __restrict__ pc, const float* __restrict__ feat,
    const float* __restrict__ tmg, const int* __restrict__ mins,
    float* __restrict__ out)
{
    const int tile = blockIdx.x, b = blockIdx.y, tid = threadIdx.x;
    const int x0 = tile * FTILE_X;

    __shared__ float t[9];
    __shared__ float hist[FHIST_F];
    if (tid < 9) t[tid] = tmg[b * 9 + tid];
#pragma unroll
    for (int i = tid; i < FHIST_F; i += 1024) hist[i] = 0.0f;
    __syncthreads();

    const int off0 = mins[b * 2 + 0];
    const int off1 = mins[b * 2 + 1];
    const float* pcb = pc + (size_t)b * 3 * NPTS;
    const float* ftb = feat + (size_t)b * 3 * NPTS;

    for (int n = tid; n < NPTS; n += 1024) {
        int gi0, gi1, rc0, rc1;
        lattice_point(t, pcb[n], pcb[NPTS + n], pcb[2 * NPTS + n], gi0, gi1, rc0, rc1);
        const int c0 = gi0 - off0;
        const int c1 = gi1 - off1;
        if ((unsigned)c0 < SS && (unsigned)c1 < SS) {
            const int x = c1 / 3;
            if ((x >> 4) == tile) {
                const int y = c0 / 3;
                const int base = (y * FTILE_X + (x - x0)) * 3;
                lds_fadd(&hist[base + 0], ftb[0 * NPTS + n]);
                lds_fadd(&hist[base + 1], ftb[1 * NPTS + n]);
                lds_fadd(&hist[base + 2], ftb[2 * NPTS + n]);
            }
        }
    }
    __syncthreads();
#pragma unroll
    for (int idx = tid; idx < FHIST_F; idx += 1024) {
        const int y   = idx / (FTILE_X * 3);
        const int rem = idx - y * (FTILE_X * 3);
        out[(size_t)(b * 128 + y) * 384 + x0 * 3 + rem] = hist[idx];
    }
}

extern "C" void kernel_launch(void* const* d_in, const int* in_sizes, int n_in,
                              void* d_out, int out_size, void* d_ws, size_t ws_size,
                              hipStream_t stream) {
    const float* pc   = (const float*)d_in[0];  // (32,3,65536) f32
    const float* feat = (const float*)d_in[1];  // (32,3,65536) f32
    const float* tm   = (const float*)d_in[2];  // (32,3,3) f32
    float* out = (float*)d_out;                 // (32,128,128,3) f32

    const size_t bins_bytes = (size_t)NB * NPTS * sizeof(uint32_t);  // 8 MB
    const size_t need = bins_bytes + 1024 * sizeof(int);

    if (ws_size >= need) {
        uint32_t* bins = (uint32_t*)d_ws;
        int* partial = (int*)((char*)d_ws + bins_bytes);

        // out must be zero: splat flush is atomic (2 chunks per cell)
        hipMemsetAsync(out, 0, (size_t)out_size * sizeof(float), stream);

        dim3 gridA(16, NB);
        bin_kernel<<<gridA, 1024, 0, stream>>>(pc, tm, bins, partial);
        dim3 gridB(NB, 4, 2);   // b fastest -> same-batch tiles on one XCD
        splat_bins_kernel<<<gridB, 1024, 0, stream>>>(bins, feat, partial, out);
    } else {
        int* mins = (int*)d_ws;  // 64 ints
        hipMemsetAsync(mins, 0x7F, 64 * sizeof(int), stream);
        dim3 grid(8, NB);
        kmin2_kernel<<<grid, 1024, 0, stream>>>(pc, tm, mins);
        dim3 gridB2(8, NB);
        splat_recompute_kernel<<<gridB2, 1024, 0, stream>>>(pc, feat, tm, mins, out);
    }
}

// Round 16
// 122.320 us; speedup vs baseline: 1.4077x; 1.4077x over previous
//
#include <hip/hip_runtime.h>
#include <stdint.h>

// Problem constants (from reference): D1=3, S=384, B=32, N=65536
#define NPTS 65536
#define NB   32
#define SS   384

// RN(1/3) in f32 = 0x3EAAAAAB
#define C3INV 0.333333343267440796f

// Fixed-point scale for histogram accumulation (R16): int LDS atomics emit a
// single native ds_add_u32 (fire-and-forget, compiler-tracked for waitcnt —
// unlike R15's inline-asm ds_add_f32 which raced the barrier, and unlike
// float atomicAdd's CAS loop). |bin sum| < ~65k -> scale 2^15 fits int32
// with margin; quantization ~1.5e-5/add, worst bin ~6e-3 << 0.5 threshold.
#define FP_SCALE 32768.0f
#define FP_INV   (1.0f / 32768.0f)

// ---- LOCKED NUMERICS (R7, passed absmax<=0.0156) ----
__device__ __forceinline__ float fmul_strict(float a, float b) {
    float r;
    asm volatile("v_mul_f32 %0, %1, %2" : "=v"(r) : "v"(a), "v"(b));
    return r;
}
__device__ __forceinline__ float fadd_strict(float a, float b) {
    float r;
    asm volatile("v_add_f32 %0, %1, %2" : "=v"(r) : "v"(a), "v"(b));
    return r;
}

__device__ __forceinline__ void lattice_point(
    const float* __restrict__ t,
    float p0, float p1, float p2,
    int& gi0, int& gi1, int& rc0, int& rc1)
{
    float e0 = fadd_strict(fadd_strict(fmul_strict(t[0], p0), fmul_strict(t[1], p1)), fmul_strict(t[2], p2));
    float e1 = fadd_strict(fadd_strict(fmul_strict(t[3], p0), fmul_strict(t[4], p1)), fmul_strict(t[5], p2));
    float e2 = fadd_strict(fadd_strict(fmul_strict(t[6], p0), fmul_strict(t[7], p1)), fmul_strict(t[8], p2));

    float g0 = __fmul_rn(rintf(__fmul_rn(e0, C3INV)), 3.0f);
    float g1 = __fmul_rn(rintf(__fmul_rn(e1, C3INV)), 3.0f);
    float g2 = __fmul_rn(rintf(__fmul_rn(e2, C3INV)), 3.0f);

    float m0 = e0 - g0, m1 = e1 - g1, m2 = e2 - g2;
    int r0 = (int)(m1 > m0) + (int)(m2 > m0);
    int r1 = (int)(m0 >= m1) + (int)(m2 > m1);

    gi0 = (int)g0;
    gi1 = (int)g1;

    const int irs = (gi0 + gi1 + (int)g2) / 3;

    if (irs > 0) {
        if (r0 >= 3 - irs) { gi0 -= 3; r0 -= 3; }
        if (r1 >= 3 - irs) { gi1 -= 3; r1 -= 3; }
    } else if (irs < 0) {
        if (r0 < -irs) { gi0 += 3; r0 += 3; }
        if (r1 < -irs) { gi1 += 3; r1 += 3; }
    }
    r0 += irs;
    r1 += irs;

    if (r0 < 0) r0 += 3;
    if (r1 < 0) r1 += 3;
    rc0 = min(2, max(0, r0));
    rc1 = min(2, max(0, r1));
}

// ceil(a/3) for any sign (exact)
__device__ __forceinline__ int icl3(int a) {
    return (a >= 0) ? (a + 2) / 3 : -((-a) / 3);
}

// ============================ FAST PATH ============================
// Kernel A: float4 pc loads (4 points/lane), uint4 bins store.
__global__ __launch_bounds__(1024) void bin_kernel(
    const float* __restrict__ pc, const float* __restrict__ tmg,
    uint32_t* __restrict__ bins, int* __restrict__ partial)
{
    const int bx  = blockIdx.x;   // 0..15
    const int b   = blockIdx.y;
    const int tid = threadIdx.x;

    __shared__ float t[9];
    if (tid < 9) t[tid] = tmg[b * 9 + tid];
    __syncthreads();

    const float* pcb = pc + (size_t)b * 3 * NPTS;
    const int v = bx * 1024 + tid;           // float4 group index

    const float4 P0 = ((const float4*)(pcb + 0 * NPTS))[v];
    const float4 P1 = ((const float4*)(pcb + 1 * NPTS))[v];
    const float4 P2 = ((const float4*)(pcb + 2 * NPTS))[v];

    int km0 = 0x7FFFFFFF, km1 = 0x7FFFFFFF;
    uint32_t pk[4];
    const float p0a[4] = {P0.x, P0.y, P0.z, P0.w};
    const float p1a[4] = {P1.x, P1.y, P1.z, P1.w};
    const float p2a[4] = {P2.x, P2.y, P2.z, P2.w};
#pragma unroll
    for (int i = 0; i < 4; ++i) {
        int gi0, gi1, rc0, rc1;
        lattice_point(t, p0a[i], p1a[i], p2a[i], gi0, gi1, rc0, rc1);
        pk[i] = (uint32_t)(((gi0 / 3 + 512) << 16) | (gi1 / 3 + 512));
        km0 = min(km0, gi0 - rc0);
        km1 = min(km1, gi1 - rc1);
    }
    ((uint4*)(bins + (size_t)b * NPTS))[v] = make_uint4(pk[0], pk[1], pk[2], pk[3]);

#pragma unroll
    for (int off = 32; off > 0; off >>= 1) {
        km0 = min(km0, __shfl_down(km0, off));
        km1 = min(km1, __shfl_down(km1, off));
    }
    __shared__ int s0[16], s1[16];
    if ((tid & 63) == 0) { s0[tid >> 6] = km0; s1[tid >> 6] = km1; }
    __syncthreads();
    if (tid == 0) {
        int m0 = s0[0], m1 = s1[0];
#pragma unroll
        for (int j = 1; j < 16; ++j) { m0 = min(m0, s0[j]); m1 = min(m1, s1[j]); }
        partial[(b * 16 + bx) * 2 + 0] = m0;
        partial[(b * 16 + bx) * 2 + 1] = m1;
    }
}

// Kernel B (R16): channel-per-block, INT fixed-point LDS histogram.
// Each block owns the full 128x128 one-channel hist (64 KB LDS).
// atomicAdd(int) on LDS = native single ds_add_u32 (no CAS loop, no
// return dep, compiler-tracked). Flush: native global int atomics into
// out itself (reinterpreted as int, pre-zeroed); convert kernel follows.
// Grid (b=32, ch=3, chunk=4): linear % 8 == b % 8 -> XCD co-location.
#define CH_HIST 16384   // 128*128 ints = 64 KB

__global__ __launch_bounds__(1024) void splat_ch_int_kernel(
    const uint32_t* __restrict__ bins, const float* __restrict__ feat,
    const int* __restrict__ partial, int* __restrict__ iout)
{
    const int b     = blockIdx.x;     // 0..31 (fastest -> XCD co-location)
    const int ch    = blockIdx.y;     // 0..2
    const int chunk = blockIdx.z;     // 0..3
    const int tid   = threadIdx.x;    // 0..1023

    __shared__ int ihist[CH_HIST];
#pragma unroll
    for (int i = tid; i < CH_HIST; i += 1024) ihist[i] = 0;

    int off0 = 0x7FFFFFFF, off1 = 0x7FFFFFFF;
#pragma unroll
    for (int j = 0; j < 16; ++j) {
        off0 = min(off0, partial[(b * 16 + j) * 2 + 0]);
        off1 = min(off1, partial[(b * 16 + j) * 2 + 1]);
    }
    __syncthreads();

    // y = s0 - ceil(off0/3), x = s1 - ceil(off1/3)  (exact; >= 0)
    const int K0 = 512 + icl3(off0);
    const int K1 = 512 + icl3(off1);

    const uint32_t* bb = bins + (size_t)b * NPTS + (size_t)chunk * (NPTS / 4);
    const float*    fb = feat + ((size_t)b * 3 + ch) * NPTS + (size_t)chunk * (NPTS / 4);

    // 16384 points / 1024 lanes / 4 per vector = 4 iterations
#pragma unroll
    for (int i = 0; i < (NPTS / 4) / 4096; ++i) {
        const int v = i * 1024 + tid;
        const uint4  U = ((const uint4 *)bb)[v];
        const float4 F = ((const float4*)fb)[v];

        const uint32_t ua[4] = {U.x, U.y, U.z, U.w};
        const float    fa[4] = {F.x, F.y, F.z, F.w};

#pragma unroll
        for (int k = 0; k < 4; ++k) {
            const int y = (int)(ua[k] >> 16) - K0;   // >= 0 by construction
            const int x = (int)(ua[k] & 0xFFFFu) - K1;
            if (y < 128 && x < 128) {
                const int q = (int)rintf(__fmul_rn(fa[k], FP_SCALE));
                atomicAdd(&ihist[(y << 7) + x], q);   // native ds_add_u32
            }
        }
    }
    __syncthreads();

    // Flush: native global int atomics into pre-zeroed int view of out.
    // out index = ((b*16384 + i) * 3 + ch), i = y*128+x.
#pragma unroll
    for (int i = tid; i < CH_HIST; i += 1024) {
        const int v = ihist[i];
        if (v != 0) atomicAdd(&iout[(size_t)((b << 14) + i) * 3 + ch], v);
    }
}

// Kernel C: in-place int -> float convert of out (each cell exactly once).
__global__ __launch_bounds__(1024) void convert_kernel(float* __restrict__ out)
{
    const int i = blockIdx.x * 1024 + threadIdx.x;   // 0 .. 1572863
    const int v = ((const int*)out)[i];
    out[i] = __fmul_rn((float)v, FP_INV);
}

// ========================= FALLBACK PATH ==========================
// Only if ws_size < bins+partial (never observed). 64 ints of ws.
#define FTILE_X 16
#define FHIST_F (128 * FTILE_X * 3)

__global__ __launch_bounds__(1024) void kmin2_kernel(
    const float* __restrict__ pc, const float* __restrict__ tmg,
    int* __restrict__ mins)
{
    const int b = blockIdx.y, bx = blockIdx.x, tid = threadIdx.x;
    __shared__ float t[9];
    if (tid < 9) t[tid] = tmg[b * 9 + tid];
    __syncthreads();

    const float* pcb = pc + (size_t)b * 3 * NPTS;
    int km0 = 0x7FFFFFFF, km1 = 0x7FFFFFFF;
    const int n0 = bx * 8192;
#pragma unroll
    for (int i = 0; i < 8; ++i) {
        const int n = n0 + i * 1024 + tid;
        int gi0, gi1, rc0, rc1;
        lattice_point(t, pcb[n], pcb[NPTS + n], pcb[2 * NPTS + n], gi0, gi1, rc0, rc1);
        km0 = min(km0, gi0 - rc0);
        km1 = min(km1, gi1 - rc1);
    }
#pragma unroll
    for (int off = 32; off > 0; off >>= 1) {
        km0 = min(km0, __shfl_down(km0, off));
        km1 = min(km1, __shfl_down(km1, off));
    }
    __shared__ int s0[16], s1[16];
    if ((tid & 63) == 0) { s0[tid >> 6] = km0; s1[tid >> 6] = km1; }
    __syncthreads();
    if (tid == 0) {
        int m0 = s0[0], m1 = s1[0];
#pragma unroll
        for (int j = 1; j < 16; ++j) { m0 = min(m0, s0[j]); m1 = min(m1, s1[j]); }
        atomicMin(&mins[b * 2 + 0], m0);
        atomicMin(&mins[b * 2 + 1], m1);
    }
}

__global__ __launch_bounds__(1024) void splat_recompute_kernel(
    const float* __restrict__ pc, const float* __restrict__ feat,
    const float* __restrict__ tmg, const int* __restrict__ mins,
    float* __restrict__ out)
{
    const int tile = blockIdx.x, b = blockIdx.y, tid = threadIdx.x;
    const int x0 = tile * FTILE_X;

    __shared__ float t[9];
    __shared__ float hist[FHIST_F];
    if (tid < 9) t[tid] = tmg[b * 9 + tid];
#pragma unroll
    for (int i = tid; i < FHIST_F; i += 1024) hist[i] = 0.0f;
    __syncthreads();

    const int off0 = mins[b * 2 + 0];
    const int off1 = mins[b * 2 + 1];
    const float* pcb = pc + (size_t)b * 3 * NPTS;
    const float* ftb = feat + (size_t)b * 3 * NPTS;

    for (int n = tid; n < NPTS; n += 1024) {
        int gi0, gi1, rc0, rc1;
        lattice_point(t, pcb[n], pcb[NPTS + n], pcb[2 * NPTS + n], gi0, gi1, rc0, rc1);
        const int c0 = gi0 - off0;
        const int c1 = gi1 - off1;
        if ((unsigned)c0 < SS && (unsigned)c1 < SS) {
            const int x = c1 / 3;
            if ((x >> 4) == tile) {
                const int y = c0 / 3;
                const int base = (y * FTILE_X + (x - x0)) * 3;
                atomicAdd(&hist[base + 0], ftb[0 * NPTS + n]);
                atomicAdd(&hist[base + 1], ftb[1 * NPTS + n]);
                atomicAdd(&hist[base + 2], ftb[2 * NPTS + n]);
            }
        }
    }
    __syncthreads();
#pragma unroll
    for (int idx = tid; idx < FHIST_F; idx += 1024) {
        const int y   = idx / (FTILE_X * 3);
        const int rem = idx - y * (FTILE_X * 3);
        out[(size_t)(b * 128 + y) * 384 + x0 * 3 + rem] = hist[idx];
    }
}

extern "C" void kernel_launch(void* const* d_in, const int* in_sizes, int n_in,
                              void* d_out, int out_size, void* d_ws, size_t ws_size,
                              hipStream_t stream) {
    const float* pc   = (const float*)d_in[0];  // (32,3,65536) f32
    const float* feat = (const float*)d_in[1];  // (32,3,65536) f32
    const float* tm   = (const float*)d_in[2];  // (32,3,3) f32
    float* out = (float*)d_out;                 // (32,128,128,3) f32

    const size_t bins_bytes = (size_t)NB * NPTS * sizeof(uint32_t);  // 8 MB
    const size_t need = bins_bytes + 1024 * sizeof(int);

    if (ws_size >= need) {
        uint32_t* bins = (uint32_t*)d_ws;
        int* partial = (int*)((char*)d_ws + bins_bytes);

        // out doubles as the int accumulator; must start at 0
        hipMemsetAsync(out, 0, (size_t)out_size * sizeof(float), stream);

        dim3 gridA(16, NB);
        bin_kernel<<<gridA, 1024, 0, stream>>>(pc, tm, bins, partial);
        dim3 gridB(NB, 3, 4);   // b fastest -> same-batch blocks on one XCD
        splat_ch_int_kernel<<<gridB, 1024, 0, stream>>>(bins, feat, partial, (int*)out);
        convert_kernel<<<(out_size + 1023) / 1024, 1024, 0, stream>>>(out);
    } else {
        int* mins = (int*)d_ws;  // 64 ints
        hipMemsetAsync(mins, 0x7F, 64 * sizeof(int), stream);
        dim3 grid(8, NB);
        kmin2_kernel<<<grid, 1024, 0, stream>>>(pc, tm, mins);
        dim3 gridB2(8, NB);
        splat_recompute_kernel<<<gridB2, 1024, 0, stream>>>(pc, feat, tm, mins, out);
    }
}